// Round 8
// baseline (41238.684 us; speedup 1.0000x reference)
//
#include <hip/hip_runtime.h>
#include <math.h>

#define DD    1024
#define BB    128
#define G3    3072
#define VOUT  8000
#define S_SRC 256
#define S_TGT 128
#define SOS   1

typedef unsigned long long u64;

// ---------------------------------------------------------------------------
// argmax packing: p = (fkey(v) << 32) | (0x7FFFFFFF - index)
// fkey = monotonic float->u32 map; max(p) == (max value, first index on tie).
// ---------------------------------------------------------------------------
__device__ __forceinline__ unsigned fkey(float f) {
    unsigned b = __float_as_uint(f);
    return (b & 0x80000000u) ? ~b : (b | 0x80000000u);
}
__device__ __forceinline__ int tok_decode(u64 p) {
    return (int)(0x7FFFFFFFu - (unsigned)(p & 0xFFFFFFFFull));
}

// ---------------------------------------------------------------------------
// init: h0 = 0; amax slot0 = SOS-packed, slots 1..S_TGT = 0
// ---------------------------------------------------------------------------
__global__ __launch_bounds__(256) void k_init(float* __restrict__ h0,
                                              u64* __restrict__ amax) {
    int idx = blockIdx.x * 256 + threadIdx.x;
    if (idx < BB * DD) h0[idx] = 0.0f;
    if (idx < (S_TGT + 1) * BB)
        amax[idx] = (idx < BB) ? (u64)(0x7FFFFFFFu - SOS) : 0ull;
}

// ---------------------------------------------------------------------------
// Encoder fused step: block j (of 256) computes gh[:, {g*1024 + 4j+c}] for
// g=0..2, c=0..3 (full K=1024) AND the GRU update of h[:, 4j..4j+4).
// gi comes pre-biased from gi_buf (hoisted chunk GEMM).
// Thread (rp = tid&63, wv = tid>>6): rows {2rp,2rp+1} x col (4j+wv) x 3 gates.
// Ws reads are wave-uniform (broadcast); As reads are ds_read_b64.
// Ping-pong h buffers: reads h_in (all cols), writes h_out (own 4 cols).
// ---------------------------------------------------------------------------
__global__ __launch_bounds__(256) void k_enc_step(
    const float* __restrict__ h_in, float* __restrict__ h_out,
    const float* __restrict__ Whh, const float* __restrict__ bhh,
    const float* __restrict__ gi_s)
{
    __shared__ float As[32][132];   // h chunk [k][m]
    __shared__ float Ws[32][16];    // W chunk [k][g*4+c]
    const int j   = blockIdx.x;
    const int tid = threadIdx.x;
    const int kq  = (tid & 7) * 4;
    const int r0  = tid >> 3;            // 0..31 (staging row base)
    const int rp  = tid & 63;            // row pair
    const int wv  = tid >> 6;            // 0..3 (column within 4)

    // W row pointer for staging threads (tid < 96): wr = tid>>3 in 0..11
    const float* Wrow = nullptr;
    if (tid < 96) {
        int wr = tid >> 3;               // g = wr>>2, c = wr&3
        Wrow = Whh + (size_t)((wr >> 2) * DD + 4 * j + (wr & 3)) * DD;
    }

    float acc[2][3] = {};
    for (int k0 = 0; k0 < DD; k0 += 32) {
        #pragma unroll
        for (int p = 0; p < 4; ++p) {
            float4 v = *reinterpret_cast<const float4*>(
                h_in + (size_t)(r0 + 32 * p) * DD + k0 + kq);
            int m = r0 + 32 * p;
            As[kq+0][m] = v.x; As[kq+1][m] = v.y; As[kq+2][m] = v.z; As[kq+3][m] = v.w;
        }
        if (tid < 96) {
            float4 v = *reinterpret_cast<const float4*>(Wrow + k0 + kq);
            int wr = tid >> 3;
            Ws[kq+0][wr] = v.x; Ws[kq+1][wr] = v.y; Ws[kq+2][wr] = v.z; Ws[kq+3][wr] = v.w;
        }
        __syncthreads();
        #pragma unroll
        for (int k = 0; k < 32; ++k) {
            float a0 = As[k][2*rp], a1 = As[k][2*rp + 1];
            float w0 = Ws[k][wv], w1 = Ws[k][4 + wv], w2 = Ws[k][8 + wv];
            acc[0][0] = fmaf(a0, w0, acc[0][0]);
            acc[0][1] = fmaf(a0, w1, acc[0][1]);
            acc[0][2] = fmaf(a0, w2, acc[0][2]);
            acc[1][0] = fmaf(a1, w0, acc[1][0]);
            acc[1][1] = fmaf(a1, w1, acc[1][1]);
            acc[1][2] = fmaf(a1, w2, acc[1][2]);
        }
        __syncthreads();
    }

    const int d = 4 * j + wv;
    const float bh0 = bhh[d], bh1 = bhh[DD + d], bh2 = bhh[2*DD + d];
    #pragma unroll
    for (int i = 0; i < 2; ++i) {
        int m = 2 * rp + i;
        size_t o = (size_t)m * G3 + d;
        float ir = gi_s[o], iz = gi_s[o + DD], in_ = gi_s[o + 2*DD];
        float hr = acc[i][0] + bh0, hz = acc[i][1] + bh1, hn = acc[i][2] + bh2;
        float r = 1.0f / (1.0f + expf(-(ir + hr)));
        float z = 1.0f / (1.0f + expf(-(iz + hz)));
        float n = tanhf(in_ + r * hn);
        h_out[(size_t)m * DD + d] = (1.0f - z) * n + z * h_in[(size_t)m * DD + d];
    }
}

// ---------------------------------------------------------------------------
// Decoder fused gates+update step: block j computes BOTH gi (emb[tok] @ Wih)
// and gh (h @ Whh) for cols {g*1024+4j+c}, then the GRU update of its 4
// h-cols. tok decoded from the packed amax slot of the previous step.
// ---------------------------------------------------------------------------
__global__ __launch_bounds__(256) void k_dec_step1(
    const float* __restrict__ emb,
    const float* __restrict__ Wih, const float* __restrict__ bih,
    const float* __restrict__ Whh, const float* __restrict__ bhh,
    const float* __restrict__ h_in, float* __restrict__ h_out,
    const u64* __restrict__ amax_in)
{
    __shared__ float Es[32][132];   // emb[tok] chunk
    __shared__ float Hs[32][132];   // h chunk
    __shared__ float Ws[32][32];    // [k][0..11 gi | 12..23 gh]
    const int j   = blockIdx.x;
    const int tid = threadIdx.x;
    const int kq  = (tid & 7) * 4;
    const int r0  = tid >> 3;
    const int rp  = tid & 63;
    const int wv  = tid >> 6;

    // embedding row pointers (token gather, decoded once)
    const float* Erow[4];
    #pragma unroll
    for (int p = 0; p < 4; ++p) {
        int tk = tok_decode(amax_in[r0 + 32 * p]);
        Erow[p] = emb + (size_t)tk * DD;
    }
    const float* Wrow = nullptr;
    if (tid < 192) {
        int wr = tid >> 3;               // 0..23
        if (wr < 12)
            Wrow = Wih + (size_t)((wr >> 2) * DD + 4 * j + (wr & 3)) * DD;
        else {
            int w2 = wr - 12;
            Wrow = Whh + (size_t)((w2 >> 2) * DD + 4 * j + (w2 & 3)) * DD;
        }
    }

    float ai[2][3] = {}, ah[2][3] = {};
    for (int k0 = 0; k0 < DD; k0 += 32) {
        #pragma unroll
        for (int p = 0; p < 4; ++p) {
            int m = r0 + 32 * p;
            float4 ve = *reinterpret_cast<const float4*>(Erow[p] + k0 + kq);
            Es[kq+0][m] = ve.x; Es[kq+1][m] = ve.y; Es[kq+2][m] = ve.z; Es[kq+3][m] = ve.w;
            float4 vh = *reinterpret_cast<const float4*>(
                h_in + (size_t)m * DD + k0 + kq);
            Hs[kq+0][m] = vh.x; Hs[kq+1][m] = vh.y; Hs[kq+2][m] = vh.z; Hs[kq+3][m] = vh.w;
        }
        if (tid < 192) {
            float4 v = *reinterpret_cast<const float4*>(Wrow + k0 + kq);
            int wr = tid >> 3;
            Ws[kq+0][wr] = v.x; Ws[kq+1][wr] = v.y; Ws[kq+2][wr] = v.z; Ws[kq+3][wr] = v.w;
        }
        __syncthreads();
        #pragma unroll
        for (int k = 0; k < 32; ++k) {
            float e0 = Es[k][2*rp], e1 = Es[k][2*rp + 1];
            float h0 = Hs[k][2*rp], h1 = Hs[k][2*rp + 1];
            float wi0 = Ws[k][wv],      wi1 = Ws[k][4 + wv],  wi2 = Ws[k][8 + wv];
            float wh0 = Ws[k][12 + wv], wh1 = Ws[k][16 + wv], wh2 = Ws[k][20 + wv];
            ai[0][0] = fmaf(e0, wi0, ai[0][0]); ai[0][1] = fmaf(e0, wi1, ai[0][1]);
            ai[0][2] = fmaf(e0, wi2, ai[0][2]);
            ai[1][0] = fmaf(e1, wi0, ai[1][0]); ai[1][1] = fmaf(e1, wi1, ai[1][1]);
            ai[1][2] = fmaf(e1, wi2, ai[1][2]);
            ah[0][0] = fmaf(h0, wh0, ah[0][0]); ah[0][1] = fmaf(h0, wh1, ah[0][1]);
            ah[0][2] = fmaf(h0, wh2, ah[0][2]);
            ah[1][0] = fmaf(h1, wh0, ah[1][0]); ah[1][1] = fmaf(h1, wh1, ah[1][1]);
            ah[1][2] = fmaf(h1, wh2, ah[1][2]);
        }
        __syncthreads();
    }

    const int d = 4 * j + wv;
    const float bi0 = bih[d], bi1 = bih[DD + d], bi2 = bih[2*DD + d];
    const float bh0 = bhh[d], bh1 = bhh[DD + d], bh2 = bhh[2*DD + d];
    #pragma unroll
    for (int i = 0; i < 2; ++i) {
        int m = 2 * rp + i;
        float ir = ai[i][0] + bi0, iz = ai[i][1] + bi1, in_ = ai[i][2] + bi2;
        float hr = ah[i][0] + bh0, hz = ah[i][1] + bh1, hn = ah[i][2] + bh2;
        float r = 1.0f / (1.0f + expf(-(ir + hr)));
        float z = 1.0f / (1.0f + expf(-(iz + hz)));
        float n = tanhf(in_ + r * hn);
        h_out[(size_t)m * DD + d] = (1.0f - z) * n + z * h_in[(size_t)m * DD + d];
    }
}

// ---------------------------------------------------------------------------
// Decoder logits + argmax: 250 blocks x 512 threads, tile 128x32 full-K.
// Micro 4x2 (b128 + b64 LDS reads). Epilogue: bias, store out, per-row
// 16-lane shfl reduce of packed (fkey,idx), one atomicMax per (row, block).
// ---------------------------------------------------------------------------
__global__ __launch_bounds__(512) void k_dec_step2(
    const float* __restrict__ h, const float* __restrict__ outW,
    const float* __restrict__ outb, float* __restrict__ outC,
    u64* __restrict__ amax_out)
{
    __shared__ float As[32][132];
    __shared__ float Bs[32][34];
    const int n0  = blockIdx.x * 32;
    const int tid = threadIdx.x;
    const int kq  = (tid & 7) * 4;
    const int rr  = tid >> 3;            // 0..63
    const int tx  = tid & 15, ty = tid >> 4;   // ty 0..31

    const float* Brow = (tid < 256)
        ? outW + (size_t)(n0 + (tid >> 3)) * DD : nullptr;

    float acc[4][2] = {};
    for (int k0 = 0; k0 < DD; k0 += 32) {
        {
            float4 v = *reinterpret_cast<const float4*>(
                h + (size_t)rr * DD + k0 + kq);
            As[kq+0][rr] = v.x; As[kq+1][rr] = v.y; As[kq+2][rr] = v.z; As[kq+3][rr] = v.w;
            float4 w = *reinterpret_cast<const float4*>(
                h + (size_t)(rr + 64) * DD + k0 + kq);
            As[kq+0][rr+64] = w.x; As[kq+1][rr+64] = w.y;
            As[kq+2][rr+64] = w.z; As[kq+3][rr+64] = w.w;
        }
        if (tid < 256) {
            float4 v = *reinterpret_cast<const float4*>(Brow + k0 + kq);
            int nr = tid >> 3;
            Bs[kq+0][nr] = v.x; Bs[kq+1][nr] = v.y; Bs[kq+2][nr] = v.z; Bs[kq+3][nr] = v.w;
        }
        __syncthreads();
        #pragma unroll
        for (int k = 0; k < 32; ++k) {
            float a[4];
            #pragma unroll
            for (int i = 0; i < 4; ++i) a[i] = As[k][4*ty + i];
            float b0 = Bs[k][2*tx], b1 = Bs[k][2*tx + 1];
            #pragma unroll
            for (int i = 0; i < 4; ++i) {
                acc[i][0] = fmaf(a[i], b0, acc[i][0]);
                acc[i][1] = fmaf(a[i], b1, acc[i][1]);
            }
        }
        __syncthreads();
    }

    const int c0 = n0 + 2 * tx;
    const float b0 = outb[c0], b1 = outb[c0 + 1];
    #pragma unroll
    for (int i = 0; i < 4; ++i) {
        int m = 4 * ty + i;
        float v0 = acc[i][0] + b0, v1 = acc[i][1] + b1;
        float2 st; st.x = v0; st.y = v1;
        *reinterpret_cast<float2*>(outC + (size_t)m * VOUT + c0) = st;
        u64 p0 = ((u64)fkey(v0) << 32) | (u64)(0x7FFFFFFFu - c0);
        u64 p1 = ((u64)fkey(v1) << 32) | (u64)(0x7FFFFFFFu - (c0 + 1));
        u64 p = p0 > p1 ? p0 : p1;
        #pragma unroll
        for (int off = 8; off > 0; off >>= 1) {
            u64 q = __shfl_xor(p, off, 16);
            if (q > p) p = q;
        }
        if (tx == 0) atomicMax(&amax_out[m], p);
    }
}

// ---------------------------------------------------------------------------
// Encoder input-projection chunk GEMM (r1-proven core): gi_buf[cs][m][n] =
// emb[src[m]] . Wih[n] + bih[n]. grid (96, CH) x 256.
// ---------------------------------------------------------------------------
__global__ __launch_bounds__(256) void k_gi_chunk(
    const float* __restrict__ emb, const int* __restrict__ src_c,
    const float* __restrict__ Wih, const float* __restrict__ bih,
    float* __restrict__ gi_buf)
{
    __shared__ float As[32][132];
    __shared__ float Bs[32][34];
    const int n0 = blockIdx.x * 32;
    const int cs = blockIdx.y;
    const int tid = threadIdx.x;
    const int kq  = (tid & 7) * 4;
    const int r0  = tid >> 3;
    const int tx  = tid & 15, ty = tid >> 4;

    const int* srow = src_c + cs * BB;
    const float* Arow[4];
    #pragma unroll
    for (int p = 0; p < 4; ++p)
        Arow[p] = emb + (size_t)srow[r0 + 32 * p] * DD;
    const float* Brow = Wih + (size_t)(n0 + r0) * DD;

    float acc[8][2] = {};
    for (int k0 = 0; k0 < DD; k0 += 32) {
        #pragma unroll
        for (int p = 0; p < 4; ++p) {
            float4 v = *reinterpret_cast<const float4*>(Arow[p] + k0 + kq);
            int m = r0 + 32 * p;
            As[kq+0][m] = v.x; As[kq+1][m] = v.y; As[kq+2][m] = v.z; As[kq+3][m] = v.w;
        }
        {
            float4 v = *reinterpret_cast<const float4*>(Brow + k0 + kq);
            Bs[kq+0][r0] = v.x; Bs[kq+1][r0] = v.y; Bs[kq+2][r0] = v.z; Bs[kq+3][r0] = v.w;
        }
        __syncthreads();
        #pragma unroll
        for (int k = 0; k < 32; ++k) {
            float a[8];
            #pragma unroll
            for (int i = 0; i < 8; ++i) a[i] = As[k][ty*8 + i];
            float bb0 = Bs[k][tx*2], bb1 = Bs[k][tx*2 + 1];
            #pragma unroll
            for (int i = 0; i < 8; ++i) {
                acc[i][0] = fmaf(a[i], bb0, acc[i][0]);
                acc[i][1] = fmaf(a[i], bb1, acc[i][1]);
            }
        }
        __syncthreads();
    }
    float* C = gi_buf + (size_t)cs * (BB * G3);
    #pragma unroll
    for (int i = 0; i < 8; ++i) {
        int m = ty * 8 + i;
        #pragma unroll
        for (int jj = 0; jj < 2; ++jj) {
            int n = n0 + tx * 2 + jj;
            C[(size_t)m * G3 + n] = acc[i][jj] + bih[n];
        }
    }
}

// ---------------------------------------------------------------------------
extern "C" void kernel_launch(void* const* d_in, const int* in_sizes, int n_in,
                              void* d_out, int out_size, void* d_ws, size_t ws_size,
                              hipStream_t stream) {
    const int*   src     = (const int*)  d_in[0];
    const float* enc_emb = (const float*)d_in[2];
    const float* eWih    = (const float*)d_in[3];
    const float* eWhh    = (const float*)d_in[4];
    const float* ebih    = (const float*)d_in[5];
    const float* ebhh    = (const float*)d_in[6];
    const float* dec_emb = (const float*)d_in[7];
    const float* dWih    = (const float*)d_in[8];
    const float* dWhh    = (const float*)d_in[9];
    const float* dbih    = (const float*)d_in[10];
    const float* dbhh    = (const float*)d_in[11];
    const float* outW    = (const float*)d_in[12];
    const float* outb    = (const float*)d_in[13];
    float* out = (float*)d_out;

    // workspace: h0, h1 (ping-pong), gi_buf (CH chunks), amax slots
    float* h0 = (float*)d_ws;
    float* h1 = h0 + BB * DD;
    float* gi_buf = h1 + BB * DD;

    size_t head = (size_t)(2 * BB * DD) * sizeof(float);
    size_t amax_bytes = (size_t)(S_TGT + 1) * BB * sizeof(u64);
    int CH = 8;
    while (CH > 1 &&
           head + (size_t)CH * BB * G3 * sizeof(float) + amax_bytes > ws_size)
        CH >>= 1;
    u64* amax = (u64*)(gi_buf + (size_t)CH * BB * G3);

    k_init<<<512, 256, 0, stream>>>(h0, amax);

    // ---- Encoder: hoisted gi chunks + fused gh+update per step ----
    for (int c = 0; c < S_SRC; c += CH) {
        k_gi_chunk<<<dim3(96, CH), 256, 0, stream>>>(enc_emb, src + c * BB,
                                                     eWih, ebih, gi_buf);
        for (int s2 = 0; s2 < CH; ++s2) {
            int s = c + s2;
            const float* hi = (s & 1) ? h1 : h0;
            float*       ho = (s & 1) ? h0 : h1;
            k_enc_step<<<256, 256, 0, stream>>>(hi, ho, eWhh, ebhh,
                                                gi_buf + (size_t)s2 * BB * G3);
        }
    }
    // after S_SRC=256 steps (even), final h is in h0

    // ---- Decoder: fused gates+update, then fused logits+argmax ----
    for (int t = 0; t < S_TGT; ++t) {
        const float* hi = (t & 1) ? h1 : h0;
        float*       ho = (t & 1) ? h0 : h1;
        k_dec_step1<<<256, 256, 0, stream>>>(dec_emb, dWih, dbih, dWhh, dbhh,
                                             hi, ho, amax + (size_t)t * BB);
        k_dec_step2<<<250, 512, 0, stream>>>(ho, outW, outb,
                                             out + (size_t)t * BB * VOUT,
                                             amax + (size_t)(t + 1) * BB);
    }
}